// Round 6
// baseline (1830.602 us; speedup 1.0000x reference)
//
#include <hip/hip_runtime.h>
#include <stdint.h>

#define N_NODES 100000
#define N_REL 8
#define NP 16          // (relation, direction) pairs
#define D 256
#define E 262144       // 2^18 edges per pair
#define MP 100096      // N padded to multiple of 128
#define NB 196         // row buckets of 512 nodes (196*512 >= 100000)
#define NB1 (NB + 1)
#define NPT 64         // gemm panel steps: 16 pairs x 4 k-panels

typedef __attribute__((ext_vector_type(8))) __bf16 bf16x8;
typedef __attribute__((ext_vector_type(4))) float f32x4;

__device__ __forceinline__ float bf2f(unsigned short u) {
    unsigned int v = ((unsigned int)u) << 16;
    return __builtin_bit_cast(float, v);
}
__device__ __forceinline__ unsigned short f2bf(float f) {
    unsigned int x = __builtin_bit_cast(unsigned int, f);
    unsigned int r = x + 0x7fffu + ((x >> 16) & 1u);   // RNE, finite inputs
    return (unsigned short)(r >> 16);
}
__device__ __forceinline__ void async16(const void* g, void* l) {
    __builtin_amdgcn_global_load_lds(
        (const __attribute__((address_space(1))) unsigned int*)g,
        (__attribute__((address_space(3))) unsigned int*)l, 16, 0, 0);
}

// ---- X (f32) -> bf16, 4 elems/thread ----
__global__ void k_conv_x(const float* __restrict__ X, unsigned short* __restrict__ Xb) {
    size_t base = ((size_t)blockIdx.x * blockDim.x + threadIdx.x) * 4;
    if (base >= (size_t)N_NODES * D) return;
    float4 v = *(const float4*)(X + base);
    ushort4 o;
    o.x = f2bf(v.x); o.y = f2bf(v.y); o.z = f2bf(v.z); o.w = f2bf(v.w);
    *(ushort4*)(Xb + base) = o;
}

// ---- W, W_t (f32 [p][k][n]) -> bf16 transposed WT[p][n][k], LDS-tiled ----
__global__ void k_conv_w(const float* __restrict__ w, const float* __restrict__ wt,
                         unsigned short* __restrict__ WT) {
    __shared__ unsigned short tile[64 * 65];
    int b = blockIdx.x;
    int p = b >> 4, t16 = b & 15;
    int k0 = (t16 >> 2) * 64, n0 = (t16 & 3) * 64;
    const float* src = (p < N_REL) ? (w + ((size_t)p << 16)) : (wt + ((size_t)(p - N_REL) << 16));
    int tid = threadIdx.x;
    #pragma unroll
    for (int pass = 0; pass < 16; ++pass) {
        int idx = pass * 256 + tid;
        int r = idx >> 6, c = idx & 63;            // r = k local, c = n local
        tile[c * 65 + r] = f2bf(src[(size_t)(k0 + r) * D + n0 + c]);
    }
    __syncthreads();
    unsigned short* dst = WT + ((size_t)p << 16);
    #pragma unroll
    for (int pass = 0; pass < 16; ++pass) {
        int idx = pass * 256 + tid;
        int rr = idx >> 6, cc = idx & 63;          // rr = n local, cc = k local
        dst[(size_t)(n0 + rr) * D + k0 + cc] = tile[rr * 65 + cc];
    }
}

// ---- bw[p][j] = sum_k bias[p][k] * W[p][k][j], exact f32 ----
__global__ void k_bw(const float* __restrict__ bias, const float* __restrict__ bias_t,
                     const float* __restrict__ w, const float* __restrict__ wt,
                     float* __restrict__ bw) {
    int p = blockIdx.x, j = threadIdx.x;
    const float* b = (p < N_REL) ? bias + p * D : bias_t + (p - N_REL) * D;
    const float* W = (p < N_REL) ? w + ((size_t)p << 16) : wt + ((size_t)(p - N_REL) << 16);
    float acc = 0.f;
    for (int k = 0; k < D; ++k) acc += b[k] * W[(k << 8) + j];
    bw[p * D + j] = acc;
}

// ==================== binned CSR build ====================
// B1: per-block LDS histogram over 196 buckets (512 nodes each) -> global bucket counts
__global__ __launch_bounds__(256) void k_bcnt(const int* __restrict__ ar, const int* __restrict__ atr,
                                              unsigned int* __restrict__ bcnt) {
    __shared__ unsigned int h[NB];
    int b = blockIdx.x;
    int p = b >> 5, blk = b & 31;       // 32 blocks/pair, 8192 edges/block
    int tid = threadIdx.x;
    const int* rows = (p < N_REL) ? ar + (size_t)p * E : atr + (size_t)(p - N_REL) * E;
    for (int i = tid; i < NB; i += 256) h[i] = 0;
    __syncthreads();
    int base = blk * 8192;
    #pragma unroll
    for (int k = 0; k < 32; ++k)
        atomicAdd(&h[((unsigned)rows[base + k * 256 + tid]) >> 9], 1u);
    __syncthreads();
    for (int i = tid; i < NB; i += 256) {
        unsigned c = h[i];
        if (c) atomicAdd(&bcnt[p * NB + i], c);
    }
}

// B2: exclusive scan of 196 bucket counts per pair -> boff (NB1 stride) + bcur init
__global__ void k_bscan(const unsigned int* __restrict__ bcnt, unsigned int* __restrict__ boff,
                        unsigned int* __restrict__ bcur) {
    __shared__ unsigned int wsum[4], wexc[4];
    int p = blockIdx.x, tid = threadIdx.x, lane = tid & 63, wv = tid >> 6;
    unsigned c = (tid < NB) ? bcnt[p * NB + tid] : 0u;
    unsigned x = c;
    #pragma unroll
    for (int d = 1; d < 64; d <<= 1) {
        unsigned t = __shfl_up(x, d, 64);
        if (lane >= d) x += t;
    }
    if (lane == 63) wsum[wv] = x;
    __syncthreads();
    if (tid == 0) {
        unsigned run = 0;
        for (int i = 0; i < 4; ++i) { unsigned t = wsum[i]; wexc[i] = run; run += t; }
    }
    __syncthreads();
    unsigned excl = wexc[wv] + x - c;
    if (tid < NB) { boff[p * NB1 + tid] = excl; bcur[p * NB + tid] = excl; }
    if (tid == NB - 1) boff[p * NB1 + NB] = excl + c;
}

// B3: re-read edges; reserve contiguous per-(block,bucket) runs (1 global atomic each);
// write packed (localrow<<17)|col into bin.
__global__ __launch_bounds__(256) void k_bfill(const int* __restrict__ ar, const int* __restrict__ ac,
                                               const int* __restrict__ atr, const int* __restrict__ atc,
                                               unsigned int* __restrict__ bcur, unsigned int* __restrict__ bin) {
    __shared__ unsigned int h[NB];
    int b = blockIdx.x;
    int p = b >> 5, blk = b & 31;
    int tid = threadIdx.x;
    const int *rows, *cols;
    if (p < N_REL) { rows = ar + (size_t)p * E;  cols = ac + (size_t)p * E; }
    else           { rows = atr + (size_t)(p - N_REL) * E; cols = atc + (size_t)(p - N_REL) * E; }
    for (int i = tid; i < NB; i += 256) h[i] = 0;
    __syncthreads();
    int base = blk * 8192;
    #pragma unroll
    for (int k = 0; k < 32; ++k)
        atomicAdd(&h[((unsigned)rows[base + k * 256 + tid]) >> 9], 1u);
    __syncthreads();
    for (int i = tid; i < NB; i += 256) {
        unsigned c = h[i];
        h[i] = c ? atomicAdd(&bcur[p * NB + i], c) : 0u;   // h becomes global cursor
    }
    __syncthreads();
    unsigned int* bp = bin + (size_t)p * E;
    #pragma unroll
    for (int k = 0; k < 32; ++k) {
        int e = base + k * 256 + tid;
        unsigned r = (unsigned)rows[e];
        unsigned slot = atomicAdd(&h[r >> 9], 1u);
        bp[slot] = ((r & 511u) << 17) | (unsigned)cols[e];
    }
}

// B4: one block per (pair,bucket): per-row count + scan of 512, emit oc and CSR slab
__global__ __launch_bounds__(256) void k_csr(const unsigned int* __restrict__ bin,
                                             const unsigned int* __restrict__ boff,
                                             unsigned int* __restrict__ csr,
                                             uint2* __restrict__ oc) {
    __shared__ unsigned int lcnt[512];
    __shared__ unsigned int lbase[512];
    __shared__ unsigned int wsum[4], wexc[4];
    int b = blockIdx.x;
    int p = b / NB, bk = b - p * NB;
    int tid = threadIdx.x, lane = tid & 63, wv = tid >> 6;
    unsigned goff = boff[p * NB1 + bk];
    unsigned m = boff[p * NB1 + bk + 1] - goff;
    lcnt[tid] = 0; lcnt[tid + 256] = 0;
    __syncthreads();
    const unsigned int* bp = bin + (size_t)p * E + goff;
    for (unsigned e = tid; e < m; e += 256) atomicAdd(&lcnt[bp[e] >> 17], 1u);
    __syncthreads();
    unsigned a0 = lcnt[2 * tid], a1 = lcnt[2 * tid + 1];
    unsigned s = a0 + a1, x = s;
    #pragma unroll
    for (int d = 1; d < 64; d <<= 1) {
        unsigned t = __shfl_up(x, d, 64);
        if (lane >= d) x += t;
    }
    if (lane == 63) wsum[wv] = x;
    __syncthreads();
    if (tid == 0) {
        unsigned run = 0;
        for (int i = 0; i < 4; ++i) { unsigned t = wsum[i]; wexc[i] = run; run += t; }
    }
    __syncthreads();
    unsigned excl = wexc[wv] + x - s;
    lbase[2 * tid] = excl;
    lbase[2 * tid + 1] = excl + a0;
    __syncthreads();
    #pragma unroll
    for (int i = 0; i < 2; ++i) {
        int li = tid + i * 256;
        int node = bk * 512 + li;
        if (node < N_NODES)
            oc[(size_t)p * N_NODES + node] = make_uint2(goff + lbase[li], lcnt[li]);
    }
    __syncthreads();
    unsigned int* cp = csr + (size_t)p * E + goff;
    for (unsigned e = tid; e < m; e += 256) {
        unsigned v = bp[e];
        unsigned slot = atomicAdd(&lbase[v >> 17], 1u);
        cp[slot] = v & 0x1FFFFu;
    }
}

// ---- aggregate: one wave per (pair, row-in-chunk): comp[lp][nl] = (1/deg) * sum X[c] ----
// grid: (rows/4, NP); comp layout [NP][cm][D] bf16
__global__ __launch_bounds__(256) void k_agg(
        const unsigned short* __restrict__ Xb, const uint2* __restrict__ oc,
        const unsigned int* __restrict__ csr, unsigned short* __restrict__ comp,
        int base, int cm) {
    int lp = blockIdx.y;
    int nl = blockIdx.x * 4 + (threadIdx.x >> 6);
    int lane = threadIdx.x & 63;
    int n = base + nl;
    float ax = 0.f, ay = 0.f, az = 0.f, aw = 0.f;
    if (n < N_NODES) {
        uint2 v = oc[(size_t)lp * N_NODES + n];
        unsigned int b = v.x, deg = v.y;
        if (deg) {
            const unsigned int* cp = csr + (size_t)lp * E + b;
            for (unsigned int e0 = 0; e0 < deg; e0 += 64) {
                unsigned int rem = deg - e0; if (rem > 64) rem = 64;
                unsigned int idx = (lane < rem) ? cp[e0 + lane] : 0u;
                for (unsigned int e2 = 0; e2 < rem; ++e2) {
                    unsigned int c = __shfl(idx, (int)e2, 64);
                    ushort4 u = *(const ushort4*)(Xb + ((size_t)c << 8) + (lane << 2));
                    ax += bf2f(u.x); ay += bf2f(u.y); az += bf2f(u.z); aw += bf2f(u.w);
                }
            }
            float s = 1.0f / (float)deg;
            ax *= s; ay *= s; az *= s; aw *= s;
        }
    }
    ushort4 o;
    o.x = f2bf(ax); o.y = f2bf(ay); o.z = f2bf(az); o.w = f2bf(aw);
    *(ushort4*)(comp + ((size_t)lp * cm + nl) * D + (lane << 2)) = o;
}

// ---- GEMM over full K=4096 (16 pairs x 256): out rows written ONCE, epi fused ----
// 128x256 tile, 8 waves. A-ONLY LDS staging (16 KB/panel, double-buffered):
// per-CU global_load_lds throughput (~4.4 B/cy measured r3/r5) is the panel-time
// cap, so B (WT, 2 MB L2/L3-resident) is loaded DIRECTLY into VGPR fragments —
// 16 B/lane, 64B-line coalesced across quads. Staged DMA bytes drop 48->16 KB.
// XOR chunk swizzle on A at global_load_lds source -> conflict-free ds_read_b128.
__global__ __launch_bounds__(512, 2) void k_gemm(
        const unsigned short* __restrict__ comp, const unsigned short* __restrict__ WT,
        const uint2* __restrict__ oc, const float* __restrict__ bw,
        float* __restrict__ out, int base, int cm) {
    __shared__ unsigned short As[2][128 * 64];   // 2 x 16 KB
    __shared__ unsigned int s_mask[128];
    __shared__ float s_inv[128];
    int rb = blockIdx.x * 128;                   // row offset within chunk
    int tid = threadIdx.x, wv = tid >> 6, lane = tid & 63;
    int fr = lane & 15, quad = lane >> 4;
    int M0 = (wv & 1) * 64, N0 = (wv >> 1) * 64;

    // epilogue prep: per-row pair mask + 1/full_deg (visible after first sync)
    if (tid < 128) {
        int gr = base + rb + tid;
        unsigned m = 0;
        if (gr < N_NODES) {
            #pragma unroll
            for (int p = 0; p < NP; ++p)
                if (oc[(size_t)p * N_NODES + gr].y) m |= 1u << p;
        }
        int fd = __popc(m);
        s_mask[tid] = m;
        s_inv[tid] = fd ? 1.0f / (float)fd : 1.0f;
    }

    f32x4 acc[4][4];
    #pragma unroll
    for (int i = 0; i < 4; ++i)
        #pragma unroll
        for (int j = 0; j < 4; ++j) { f32x4 z = {0.f, 0.f, 0.f, 0.f}; acc[i][j] = z; }

    auto stageA = [&](int pt, int b) {
        int lp = pt >> 2, k0 = (pt & 3) << 6;
        const unsigned short* Ab = comp + ((size_t)lp * cm + rb) * D + k0;
        #pragma unroll
        for (int pass = 0; pass < 2; ++pass) {   // A: 128 rows x 8 chunks (2 loads/thread)
            int L = pass * 512 + tid;
            int row = L >> 3, pc = L & 7, gc = pc ^ (row & 7);
            async16(Ab + (size_t)row * D + gc * 8, &As[b][L * 8]);
        }
    };

    stageA(0, 0);
    __syncthreads();                              // panel 0 staged + masks visible
    int buf = 0;
    for (int pt = 0; pt < NPT; ++pt) {
        if (pt + 1 < NPT) stageA(pt + 1, buf ^ 1);   // DMA next A-panel
        int lp = pt >> 2, k0 = (pt & 3) << 6;
        const unsigned short* Bb = WT + ((size_t)lp << 16);
        // B fragments direct from global (L2): B[n = N0+j*16+fr][k0+kk+quad*8 ..+7]
        bf16x8 bfv[2][4];
        #pragma unroll
        for (int kx = 0; kx < 2; ++kx)
            #pragma unroll
            for (int j = 0; j < 4; ++j)
                bfv[kx][j] = *(const bf16x8*)(
                    Bb + (size_t)(N0 + j * 16 + fr) * D + k0 + kx * 32 + quad * 8);
        #pragma unroll
        for (int kx = 0; kx < 2; ++kx) {
            int kk = kx * 32;
            int wc = (kk >> 3) + quad;            // wanted global chunk
            int pc = wc ^ (fr & 7);               // swizzled phys chunk
            bf16x8 af[4];
            #pragma unroll
            for (int i = 0; i < 4; ++i)
                af[i] = *(const bf16x8*)(&As[buf][(M0 + i * 16 + fr) * 64 + pc * 8]);
            #pragma unroll
            for (int i = 0; i < 4; ++i)
                #pragma unroll
                for (int j = 0; j < 4; ++j)
                    acc[i][j] = __builtin_amdgcn_mfma_f32_16x16x32_bf16(af[i], bfv[kx][j], acc[i][j], 0, 0, 0);
        }
        __syncthreads();   // next A-panel staged (vmcnt drained); buf readers done
        buf ^= 1;
    }

    // fused epilogue: out = (acc + sum_{p in mask} bw[p]) * inv_full_deg
    float bwv[NP][4];
    #pragma unroll
    for (int p = 0; p < NP; ++p)
        #pragma unroll
        for (int j = 0; j < 4; ++j)
            bwv[p][j] = bw[p * D + N0 + j * 16 + fr];
    #pragma unroll
    for (int i = 0; i < 4; ++i) {
        #pragma unroll
        for (int r = 0; r < 4; ++r) {
            int lrow = M0 + i * 16 + quad * 4 + r;
            int gr = base + rb + lrow;
            if (gr < N_NODES) {
                unsigned m = s_mask[lrow];
                float inv = s_inv[lrow];
                #pragma unroll
                for (int j = 0; j < 4; ++j) {
                    float bsum = 0.f;
                    #pragma unroll
                    for (int p = 0; p < NP; ++p)
                        if ((m >> p) & 1u) bsum += bwv[p][j];
                    int col = N0 + j * 16 + fr;
                    out[(size_t)gr * D + col] = (acc[i][j][r] + bsum) * inv;
                }
            }
        }
    }
}

extern "C" void kernel_launch(void* const* d_in, const int* in_sizes, int n_in,
                              void* d_out, int out_size, void* d_ws, size_t ws_size,
                              hipStream_t stream) {
    (void)in_sizes; (void)n_in; (void)out_size;
    const float* X      = (const float*)d_in[0];
    const float* w      = (const float*)d_in[1];
    const float* bias   = (const float*)d_in[2];
    const float* wt     = (const float*)d_in[3];
    const float* bias_t = (const float*)d_in[4];
    const int* ar  = (const int*)d_in[5];
    const int* ac  = (const int*)d_in[6];
    const int* atr = (const int*)d_in[7];
    const int* atc = (const int*)d_in[8];
    float* out = (float*)d_out;

    char* ws = (char*)d_ws;
    size_t o = 0;
    auto alloc = [&](size_t bytes) -> char* {
        char* p = ws + o;
        o = (o + bytes + 255) & ~(size_t)255;
        return p;
    };
    unsigned short* Xb   = (unsigned short*)alloc((size_t)N_NODES * D * 2);
    unsigned short* WT   = (unsigned short*)alloc((size_t)NP * D * D * 2);
    float*          bw   = (float*)alloc((size_t)NP * D * 4);
    uint2*          oc   = (uint2*)alloc((size_t)NP * N_NODES * 8);
    unsigned int*   csr  = (unsigned int*)alloc((size_t)NP * E * 4);
    unsigned int*   bin  = (unsigned int*)alloc((size_t)NP * E * 4);
    unsigned int*   bcnt = (unsigned int*)alloc((size_t)NP * NB * 4);
    unsigned int*   boff = (unsigned int*)alloc((size_t)NP * NB1 * 4);
    unsigned int*   bcur = (unsigned int*)alloc((size_t)NP * NB * 4);
    size_t fixed = o;
    // row-chunk size: as many 128-row groups as fit; comp = [NP][cm][D] bf16
    size_t per_row = (size_t)NP * D * 2;    // 8192 B per chunk-row
    size_t avail = (ws_size > fixed) ? (ws_size - fixed) : 0;
    long long cmL = (long long)(avail / per_row) & ~127LL;
    if (cmL < 128) cmL = 128;               // workspace guaranteed larger in practice
    if (cmL > MP) cmL = MP;
    int cm = (int)cmL;
    unsigned short* comp = (unsigned short*)(ws + fixed);

    hipMemsetAsync(bcnt, 0, (size_t)NP * NB * 4, stream);
    k_conv_x<<<(N_NODES * D / 4 + 255) / 256, 256, 0, stream>>>(X, Xb);
    k_conv_w<<<NP * 16, 256, 0, stream>>>(w, wt, WT);
    k_bw<<<NP, 256, 0, stream>>>(bias, bias_t, w, wt, bw);
    k_bcnt<<<NP * 32, 256, 0, stream>>>(ar, atr, bcnt);
    k_bscan<<<NP, 256, 0, stream>>>(bcnt, boff, bcur);
    k_bfill<<<NP * 32, 256, 0, stream>>>(ar, ac, atr, atc, bcur, bin);
    k_csr<<<NP * NB, 256, 0, stream>>>(bin, boff, csr, oc);
    for (int base = 0; base < MP; base += cm) {
        int rows = MP - base; if (rows > cm) rows = cm;   // multiple of 128
        if (rows <= 0) break;
        k_agg<<<dim3(rows / 4, NP), 256, 0, stream>>>(Xb, oc, csr, comp, base, cm);
        k_gemm<<<rows / 128, 512, 0, stream>>>(comp, WT, oc, bw, out, base, cm);
    }
}

// Round 7
// 1526.460 us; speedup vs baseline: 1.1992x; 1.1992x over previous
//
#include <hip/hip_runtime.h>
#include <stdint.h>

#define N_NODES 100000
#define N_REL 8
#define NP 16          // (relation, direction) pairs
#define D 256
#define E 262144       // 2^18 edges per pair
#define MP 100096      // N padded to multiple of 128
#define NB 196         // row buckets of 512 nodes (196*512 >= 100000)
#define NB1 (NB + 1)
#define NPT 64         // gemm panel steps: 16 pairs x 4 k-panels

typedef __attribute__((ext_vector_type(8))) __bf16 bf16x8;
typedef __attribute__((ext_vector_type(4))) float f32x4;

__device__ __forceinline__ float bf2f(unsigned short u) {
    unsigned int v = ((unsigned int)u) << 16;
    return __builtin_bit_cast(float, v);
}
__device__ __forceinline__ unsigned short f2bf(float f) {
    unsigned int x = __builtin_bit_cast(unsigned int, f);
    unsigned int r = x + 0x7fffu + ((x >> 16) & 1u);   // RNE, finite inputs
    return (unsigned short)(r >> 16);
}
__device__ __forceinline__ void async16(const void* g, void* l) {
    __builtin_amdgcn_global_load_lds(
        (const __attribute__((address_space(1))) unsigned int*)g,
        (__attribute__((address_space(3))) unsigned int*)l, 16, 0, 0);
}

// ---- X (f32) -> bf16, 4 elems/thread ----
__global__ void k_conv_x(const float* __restrict__ X, unsigned short* __restrict__ Xb) {
    size_t base = ((size_t)blockIdx.x * blockDim.x + threadIdx.x) * 4;
    if (base >= (size_t)N_NODES * D) return;
    float4 v = *(const float4*)(X + base);
    ushort4 o;
    o.x = f2bf(v.x); o.y = f2bf(v.y); o.z = f2bf(v.z); o.w = f2bf(v.w);
    *(ushort4*)(Xb + base) = o;
}

// ---- W, W_t (f32 [p][k][n]) -> bf16 transposed WT[p][n][k], LDS-tiled ----
__global__ void k_conv_w(const float* __restrict__ w, const float* __restrict__ wt,
                         unsigned short* __restrict__ WT) {
    __shared__ unsigned short tile[64 * 65];
    int b = blockIdx.x;
    int p = b >> 4, t16 = b & 15;
    int k0 = (t16 >> 2) * 64, n0 = (t16 & 3) * 64;
    const float* src = (p < N_REL) ? (w + ((size_t)p << 16)) : (wt + ((size_t)(p - N_REL) << 16));
    int tid = threadIdx.x;
    #pragma unroll
    for (int pass = 0; pass < 16; ++pass) {
        int idx = pass * 256 + tid;
        int r = idx >> 6, c = idx & 63;            // r = k local, c = n local
        tile[c * 65 + r] = f2bf(src[(size_t)(k0 + r) * D + n0 + c]);
    }
    __syncthreads();
    unsigned short* dst = WT + ((size_t)p << 16);
    #pragma unroll
    for (int pass = 0; pass < 16; ++pass) {
        int idx = pass * 256 + tid;
        int rr = idx >> 6, cc = idx & 63;          // rr = n local, cc = k local
        dst[(size_t)(n0 + rr) * D + k0 + cc] = tile[rr * 65 + cc];
    }
}

// ---- bw[p][j] = sum_k bias[p][k] * W[p][k][j], exact f32 ----
__global__ void k_bw(const float* __restrict__ bias, const float* __restrict__ bias_t,
                     const float* __restrict__ w, const float* __restrict__ wt,
                     float* __restrict__ bw) {
    int p = blockIdx.x, j = threadIdx.x;
    const float* b = (p < N_REL) ? bias + p * D : bias_t + (p - N_REL) * D;
    const float* W = (p < N_REL) ? w + ((size_t)p << 16) : wt + ((size_t)(p - N_REL) << 16);
    float acc = 0.f;
    for (int k = 0; k < D; ++k) acc += b[k] * W[(k << 8) + j];
    bw[p * D + j] = acc;
}

// ==================== binned CSR build ====================
// B1: per-block LDS histogram over 196 buckets (512 nodes each) -> global bucket counts
__global__ __launch_bounds__(256) void k_bcnt(const int* __restrict__ ar, const int* __restrict__ atr,
                                              unsigned int* __restrict__ bcnt) {
    __shared__ unsigned int h[NB];
    int b = blockIdx.x;
    int p = b >> 5, blk = b & 31;       // 32 blocks/pair, 8192 edges/block
    int tid = threadIdx.x;
    const int* rows = (p < N_REL) ? ar + (size_t)p * E : atr + (size_t)(p - N_REL) * E;
    for (int i = tid; i < NB; i += 256) h[i] = 0;
    __syncthreads();
    int base = blk * 8192;
    #pragma unroll
    for (int k = 0; k < 32; ++k)
        atomicAdd(&h[((unsigned)rows[base + k * 256 + tid]) >> 9], 1u);
    __syncthreads();
    for (int i = tid; i < NB; i += 256) {
        unsigned c = h[i];
        if (c) atomicAdd(&bcnt[p * NB + i], c);
    }
}

// B2: exclusive scan of 196 bucket counts per pair -> boff (NB1 stride) + bcur init
__global__ void k_bscan(const unsigned int* __restrict__ bcnt, unsigned int* __restrict__ boff,
                        unsigned int* __restrict__ bcur) {
    __shared__ unsigned int wsum[4], wexc[4];
    int p = blockIdx.x, tid = threadIdx.x, lane = tid & 63, wv = tid >> 6;
    unsigned c = (tid < NB) ? bcnt[p * NB + tid] : 0u;
    unsigned x = c;
    #pragma unroll
    for (int d = 1; d < 64; d <<= 1) {
        unsigned t = __shfl_up(x, d, 64);
        if (lane >= d) x += t;
    }
    if (lane == 63) wsum[wv] = x;
    __syncthreads();
    if (tid == 0) {
        unsigned run = 0;
        for (int i = 0; i < 4; ++i) { unsigned t = wsum[i]; wexc[i] = run; run += t; }
    }
    __syncthreads();
    unsigned excl = wexc[wv] + x - c;
    if (tid < NB) { boff[p * NB1 + tid] = excl; bcur[p * NB + tid] = excl; }
    if (tid == NB - 1) boff[p * NB1 + NB] = excl + c;
}

// B3: re-read edges; reserve contiguous per-(block,bucket) runs (1 global atomic each);
// write packed (localrow<<17)|col into bin.
__global__ __launch_bounds__(256) void k_bfill(const int* __restrict__ ar, const int* __restrict__ ac,
                                               const int* __restrict__ atr, const int* __restrict__ atc,
                                               unsigned int* __restrict__ bcur, unsigned int* __restrict__ bin) {
    __shared__ unsigned int h[NB];
    int b = blockIdx.x;
    int p = b >> 5, blk = b & 31;
    int tid = threadIdx.x;
    const int *rows, *cols;
    if (p < N_REL) { rows = ar + (size_t)p * E;  cols = ac + (size_t)p * E; }
    else           { rows = atr + (size_t)(p - N_REL) * E; cols = atc + (size_t)(p - N_REL) * E; }
    for (int i = tid; i < NB; i += 256) h[i] = 0;
    __syncthreads();
    int base = blk * 8192;
    #pragma unroll
    for (int k = 0; k < 32; ++k)
        atomicAdd(&h[((unsigned)rows[base + k * 256 + tid]) >> 9], 1u);
    __syncthreads();
    for (int i = tid; i < NB; i += 256) {
        unsigned c = h[i];
        h[i] = c ? atomicAdd(&bcur[p * NB + i], c) : 0u;   // h becomes global cursor
    }
    __syncthreads();
    unsigned int* bp = bin + (size_t)p * E;
    #pragma unroll
    for (int k = 0; k < 32; ++k) {
        int e = base + k * 256 + tid;
        unsigned r = (unsigned)rows[e];
        unsigned slot = atomicAdd(&h[r >> 9], 1u);
        bp[slot] = ((r & 511u) << 17) | (unsigned)cols[e];
    }
}

// B4: one block per (pair,bucket): per-row count + scan of 512, emit oc and CSR slab
__global__ __launch_bounds__(256) void k_csr(const unsigned int* __restrict__ bin,
                                             const unsigned int* __restrict__ boff,
                                             unsigned int* __restrict__ csr,
                                             uint2* __restrict__ oc) {
    __shared__ unsigned int lcnt[512];
    __shared__ unsigned int lbase[512];
    __shared__ unsigned int wsum[4], wexc[4];
    int b = blockIdx.x;
    int p = b / NB, bk = b - p * NB;
    int tid = threadIdx.x, lane = tid & 63, wv = tid >> 6;
    unsigned goff = boff[p * NB1 + bk];
    unsigned m = boff[p * NB1 + bk + 1] - goff;
    lcnt[tid] = 0; lcnt[tid + 256] = 0;
    __syncthreads();
    const unsigned int* bp = bin + (size_t)p * E + goff;
    for (unsigned e = tid; e < m; e += 256) atomicAdd(&lcnt[bp[e] >> 17], 1u);
    __syncthreads();
    unsigned a0 = lcnt[2 * tid], a1 = lcnt[2 * tid + 1];
    unsigned s = a0 + a1, x = s;
    #pragma unroll
    for (int d = 1; d < 64; d <<= 1) {
        unsigned t = __shfl_up(x, d, 64);
        if (lane >= d) x += t;
    }
    if (lane == 63) wsum[wv] = x;
    __syncthreads();
    if (tid == 0) {
        unsigned run = 0;
        for (int i = 0; i < 4; ++i) { unsigned t = wsum[i]; wexc[i] = run; run += t; }
    }
    __syncthreads();
    unsigned excl = wexc[wv] + x - s;
    lbase[2 * tid] = excl;
    lbase[2 * tid + 1] = excl + a0;
    __syncthreads();
    #pragma unroll
    for (int i = 0; i < 2; ++i) {
        int li = tid + i * 256;
        int node = bk * 512 + li;
        if (node < N_NODES)
            oc[(size_t)p * N_NODES + node] = make_uint2(goff + lbase[li], lcnt[li]);
    }
    __syncthreads();
    unsigned int* cp = csr + (size_t)p * E + goff;
    for (unsigned e = tid; e < m; e += 256) {
        unsigned v = bp[e];
        unsigned slot = atomicAdd(&lbase[v >> 17], 1u);
        cp[slot] = v & 0x1FFFFu;
    }
}

// ---- aggregate: one wave per (pair, row-in-chunk): comp[lp][nl] = (1/deg) * sum X[c] ----
// grid: (rows/4, NP); comp layout [NP][cm][D] bf16
__global__ __launch_bounds__(256) void k_agg(
        const unsigned short* __restrict__ Xb, const uint2* __restrict__ oc,
        const unsigned int* __restrict__ csr, unsigned short* __restrict__ comp,
        int base, int cm) {
    int lp = blockIdx.y;
    int nl = blockIdx.x * 4 + (threadIdx.x >> 6);
    int lane = threadIdx.x & 63;
    int n = base + nl;
    float ax = 0.f, ay = 0.f, az = 0.f, aw = 0.f;
    if (n < N_NODES) {
        uint2 v = oc[(size_t)lp * N_NODES + n];
        unsigned int b = v.x, deg = v.y;
        if (deg) {
            const unsigned int* cp = csr + (size_t)lp * E + b;
            for (unsigned int e0 = 0; e0 < deg; e0 += 64) {
                unsigned int rem = deg - e0; if (rem > 64) rem = 64;
                unsigned int idx = (lane < rem) ? cp[e0 + lane] : 0u;
                for (unsigned int e2 = 0; e2 < rem; ++e2) {
                    unsigned int c = __shfl(idx, (int)e2, 64);
                    ushort4 u = *(const ushort4*)(Xb + ((size_t)c << 8) + (lane << 2));
                    ax += bf2f(u.x); ay += bf2f(u.y); az += bf2f(u.z); aw += bf2f(u.w);
                }
            }
            float s = 1.0f / (float)deg;
            ax *= s; ay *= s; az *= s; aw *= s;
        }
    }
    ushort4 o;
    o.x = f2bf(ax); o.y = f2bf(ay); o.z = f2bf(az); o.w = f2bf(aw);
    *(ushort4*)(comp + ((size_t)lp * cm + nl) * D + (lane << 2)) = o;
}

// ---- GEMM over full K=4096 (16 pairs x 256): out rows written ONCE, epi fused ----
// 64x256 tile, 4 waves (each 64M x 64N), 256 threads, up to 3 blocks/CU
// (launch_bounds(256,3); LDS ~17 KB). Per-block global_load_lds stream rate is
// ~4-8 B/cy (r3/r5/r6 measurement) -> throughput comes from MULTIPLE independent
// blocks per CU whose barrier drains overlap (m97's mechanism), not from in-block
// pipelining (r5 null). A-only LDS staging (8 KB/panel, dbuf). B read directly
// from L2 into VGPRs; bfv loads are issued BEFORE the stageA DMA (sched_barrier
// pins the order) so the vmcnt FIFO retires bfv without draining the prefetch —
// this was r6's serialization bug.
__global__ __launch_bounds__(256, 3) void k_gemm(
        const unsigned short* __restrict__ comp, const unsigned short* __restrict__ WT,
        const uint2* __restrict__ oc, const float* __restrict__ bw,
        float* __restrict__ out, int base, int cm) {
    __shared__ unsigned short As[2][64 * 64];    // 2 x 8 KB
    __shared__ unsigned int s_mask[64];
    __shared__ float s_inv[64];
    int rb = blockIdx.x * 64;                    // row offset within chunk
    int tid = threadIdx.x, wv = tid >> 6, lane = tid & 63;
    int fr = lane & 15, quad = lane >> 4;
    int N0 = wv * 64;                            // wave's N-slice

    // epilogue prep: per-row pair mask + 1/full_deg (visible after first sync)
    if (tid < 64) {
        int gr = base + rb + tid;
        unsigned m = 0;
        if (gr < N_NODES) {
            #pragma unroll
            for (int p = 0; p < NP; ++p)
                if (oc[(size_t)p * N_NODES + gr].y) m |= 1u << p;
        }
        int fd = __popc(m);
        s_mask[tid] = m;
        s_inv[tid] = fd ? 1.0f / (float)fd : 1.0f;
    }

    f32x4 acc[4][4];
    #pragma unroll
    for (int i = 0; i < 4; ++i)
        #pragma unroll
        for (int j = 0; j < 4; ++j) { f32x4 z = {0.f, 0.f, 0.f, 0.f}; acc[i][j] = z; }

    auto stageA = [&](int pt, int b) {
        int lp = pt >> 2, k0 = (pt & 3) << 6;
        const unsigned short* Ab = comp + ((size_t)lp * cm + rb) * D + k0;
        #pragma unroll
        for (int pass = 0; pass < 2; ++pass) {   // A: 64 rows x 8 chunks (2 loads/thread)
            int L = pass * 256 + tid;
            int row = L >> 3, pc = L & 7, gc = pc ^ (row & 7);
            async16(Ab + (size_t)row * D + gc * 8, &As[b][L * 8]);
        }
    };

    stageA(0, 0);
    __syncthreads();                              // panel 0 staged + masks visible
    int buf = 0;
    for (int pt = 0; pt < NPT; ++pt) {
        int lp = pt >> 2, k0 = (pt & 3) << 6;
        const unsigned short* Bb = WT + ((size_t)lp << 16);
        // B fragments direct from global (L2-resident WT), ISSUED FIRST:
        // B[n = N0+j*16+fr][k0 + kx*32 + quad*8 .. +7]
        bf16x8 bfv[2][4];
        #pragma unroll
        for (int kx = 0; kx < 2; ++kx)
            #pragma unroll
            for (int j = 0; j < 4; ++j)
                bfv[kx][j] = *(const bf16x8*)(
                    Bb + (size_t)(N0 + j * 16 + fr) * D + k0 + kx * 32 + quad * 8);
        __builtin_amdgcn_sched_barrier(0);        // keep bfv issue BEFORE the DMA
        if (pt + 1 < NPT) stageA(pt + 1, buf ^ 1);   // prefetch next A-panel (newer in FIFO)
        #pragma unroll
        for (int kx = 0; kx < 2; ++kx) {
            int kk = kx * 32;
            int wc = (kk >> 3) + quad;            // wanted global chunk
            int pc = wc ^ (fr & 7);               // swizzled phys chunk
            bf16x8 af[4];
            #pragma unroll
            for (int i = 0; i < 4; ++i)
                af[i] = *(const bf16x8*)(&As[buf][(i * 16 + fr) * 64 + pc * 8]);
            #pragma unroll
            for (int i = 0; i < 4; ++i)
                #pragma unroll
                for (int j = 0; j < 4; ++j)
                    acc[i][j] = __builtin_amdgcn_mfma_f32_16x16x32_bf16(af[i], bfv[kx][j], acc[i][j], 0, 0, 0);
        }
        __syncthreads();   // next A-panel staged (vmcnt drained); buf readers done
        buf ^= 1;
    }

    // fused epilogue: out = (acc + sum_{p in mask} bw[p]) * inv_full_deg
    float bwv[NP][4];
    #pragma unroll
    for (int p = 0; p < NP; ++p)
        #pragma unroll
        for (int j = 0; j < 4; ++j)
            bwv[p][j] = bw[p * D + N0 + j * 16 + fr];
    #pragma unroll
    for (int i = 0; i < 4; ++i) {
        #pragma unroll
        for (int r = 0; r < 4; ++r) {
            int lrow = i * 16 + quad * 4 + r;
            int gr = base + rb + lrow;
            if (gr < N_NODES) {
                unsigned m = s_mask[lrow];
                float inv = s_inv[lrow];
                #pragma unroll
                for (int j = 0; j < 4; ++j) {
                    float bsum = 0.f;
                    #pragma unroll
                    for (int p = 0; p < NP; ++p)
                        if ((m >> p) & 1u) bsum += bwv[p][j];
                    int col = N0 + j * 16 + fr;
                    out[(size_t)gr * D + col] = (acc[i][j][r] + bsum) * inv;
                }
            }
        }
    }
}

extern "C" void kernel_launch(void* const* d_in, const int* in_sizes, int n_in,
                              void* d_out, int out_size, void* d_ws, size_t ws_size,
                              hipStream_t stream) {
    (void)in_sizes; (void)n_in; (void)out_size;
    const float* X      = (const float*)d_in[0];
    const float* w      = (const float*)d_in[1];
    const float* bias   = (const float*)d_in[2];
    const float* wt     = (const float*)d_in[3];
    const float* bias_t = (const float*)d_in[4];
    const int* ar  = (const int*)d_in[5];
    const int* ac  = (const int*)d_in[6];
    const int* atr = (const int*)d_in[7];
    const int* atc = (const int*)d_in[8];
    float* out = (float*)d_out;

    char* ws = (char*)d_ws;
    size_t o = 0;
    auto alloc = [&](size_t bytes) -> char* {
        char* p = ws + o;
        o = (o + bytes + 255) & ~(size_t)255;
        return p;
    };
    unsigned short* Xb   = (unsigned short*)alloc((size_t)N_NODES * D * 2);
    unsigned short* WT   = (unsigned short*)alloc((size_t)NP * D * D * 2);
    float*          bw   = (float*)alloc((size_t)NP * D * 4);
    uint2*          oc   = (uint2*)alloc((size_t)NP * N_NODES * 8);
    unsigned int*   csr  = (unsigned int*)alloc((size_t)NP * E * 4);
    unsigned int*   bin  = (unsigned int*)alloc((size_t)NP * E * 4);
    unsigned int*   bcnt = (unsigned int*)alloc((size_t)NP * NB * 4);
    unsigned int*   boff = (unsigned int*)alloc((size_t)NP * NB1 * 4);
    unsigned int*   bcur = (unsigned int*)alloc((size_t)NP * NB * 4);
    size_t fixed = o;
    // row-chunk size: as many 128-row groups as fit; comp = [NP][cm][D] bf16
    size_t per_row = (size_t)NP * D * 2;    // 8192 B per chunk-row
    size_t avail = (ws_size > fixed) ? (ws_size - fixed) : 0;
    long long cmL = (long long)(avail / per_row) & ~127LL;
    if (cmL < 128) cmL = 128;               // workspace guaranteed larger in practice
    if (cmL > MP) cmL = MP;
    int cm = (int)cmL;
    unsigned short* comp = (unsigned short*)(ws + fixed);

    hipMemsetAsync(bcnt, 0, (size_t)NP * NB * 4, stream);
    k_conv_x<<<(N_NODES * D / 4 + 255) / 256, 256, 0, stream>>>(X, Xb);
    k_conv_w<<<NP * 16, 256, 0, stream>>>(w, wt, WT);
    k_bw<<<NP, 256, 0, stream>>>(bias, bias_t, w, wt, bw);
    k_bcnt<<<NP * 32, 256, 0, stream>>>(ar, atr, bcnt);
    k_bscan<<<NP, 256, 0, stream>>>(bcnt, boff, bcur);
    k_bfill<<<NP * 32, 256, 0, stream>>>(ar, ac, atr, atc, bcur, bin);
    k_csr<<<NP * NB, 256, 0, stream>>>(bin, boff, csr, oc);
    for (int base = 0; base < MP; base += cm) {
        int rows = MP - base; if (rows > cm) rows = cm;   // multiple of 128
        if (rows <= 0) break;
        k_agg<<<dim3(rows / 4, NP), 256, 0, stream>>>(Xb, oc, csr, comp, base, cm);
        k_gemm<<<rows / 64, 256, 0, stream>>>(comp, WT, oc, bw, out, base, cm);
    }
}